// Round 8
// baseline (4104.808 us; speedup 1.0000x reference)
//
#include <hip/hip_runtime.h>
#include <hip/hip_bf16.h>
#include <math.h>

// Problem constants
#define B_   32
#define S_   512
#define IN_  128
#define H_   512
#define NH_  8
#define HD_  64
#define FF_  2048
#define NL_  2
#define DT_  0.1f
#define M_   (B_ * S_)   // 16384 rows

typedef __bf16 bf16x8 __attribute__((ext_vector_type(8)));
typedef __bf16 bf16x4 __attribute__((ext_vector_type(4)));
typedef float  f32x4  __attribute__((ext_vector_type(4)));

static __device__ __forceinline__ float relu_(float v) { return v > 0.f ? v : 0.f; }

// tanh via exp2-backed __expf; clamp keeps e finite (ref is fp32 jnp.tanh)
static __device__ __forceinline__ float tanh_fast(float x) {
    const float xc = fminf(fmaxf(x, -15.f), 15.f);
    const float e  = __expf(2.f * xc);
    return (e - 1.f) / (e + 1.f);
}

// ---------------------------------------------------------------------------
// split f32 -> (bf16 hi, bf16 lo).  lo = residual, combined ~2^-18 rel error.
// ---------------------------------------------------------------------------
__global__ __launch_bounds__(256) void split_kernel(
    const float* __restrict__ src, __bf16* __restrict__ dh,
    __bf16* __restrict__ dl, int n)
{
    const int i = (blockIdx.x * 256 + threadIdx.x) * 4;
    if (i >= n) return;
    const float4 v = *(const float4*)(src + i);
    bf16x4 h, l;
    h[0] = (__bf16)v.x; l[0] = (__bf16)(v.x - (float)h[0]);
    h[1] = (__bf16)v.y; l[1] = (__bf16)(v.y - (float)h[1]);
    h[2] = (__bf16)v.z; l[2] = (__bf16)(v.z - (float)h[2]);
    h[3] = (__bf16)v.w; l[3] = (__bf16)(v.w - (float)h[3]);
    *(bf16x4*)(dh + i) = h;
    *(bf16x4*)(dl + i) = l;
}

// ---------------------------------------------------------------------------
// Split-bf16 MFMA GEMM: C[M,N] = act(A @ W^T + bias), A=[M,K] W=[N,K] (bf16
// hi/lo pairs).  acc += Ah*Wh + Ah*Wl + Al*Wh (3x mfma_f32_16x16x32_bf16).
// Block: 256 thr (4 waves 2x2), tile 128x128, BK=32, LDS double-buffered,
// staged via global_load_lds(16B) with pre-swizzled global source so that
// ds_read_b128 fragment reads are bank-conflict-free (2-way alias only).
// WMODE: 0 = f32 C only, 1 = f32 + split bf16, 2 = split only.
// ---------------------------------------------------------------------------
template<int ACT, int WMODE>
__global__ __launch_bounds__(256, 2) void gemm_split_kernel(
    const __bf16* __restrict__ Ah, const __bf16* __restrict__ Al,
    const __bf16* __restrict__ Wh, const __bf16* __restrict__ Wl,
    const float* __restrict__ bias, float* __restrict__ C,
    __bf16* __restrict__ Ch, __bf16* __restrict__ Cl,
    int M, int N, int K)
{
    // [buf][matrix: 0=Ah 1=Al 2=Wh 3=Wl][128 rows x 32 k] bf16 (8KB each)
    __shared__ __bf16 lds[2][4][4096];

    const int tid  = threadIdx.x;
    const int l    = tid & 63;
    const int wv   = tid >> 6;          // wave 0..3
    const int n0   = blockIdx.x * 128;
    const int m0   = blockIdx.y * 128;
    const int wm   = (wv >> 1) * 64;    // wave tile origin
    const int wn   = (wv & 1) * 64;

    // staging lane constants (global side carries the swizzle)
    const int srow  = l >> 2;           // 0..15 row within 16-row group
    const int sslot = l & 3;            // 16B slot

    // fragment read byte-offsets within one 8KB matrix tile (swizzled)
    int aoff[4], woff[4];
#pragma unroll
    for (int f = 0; f < 4; ++f) {
        const int ra = wm + f * 16 + (l & 15);
        aoff[f] = ra * 64 + ((((l >> 4) ^ ((ra >> 1) & 3))) << 4);
        const int rw = wn + f * 16 + (l & 15);
        woff[f] = rw * 64 + ((((l >> 4) ^ ((rw >> 1) & 3))) << 4);
    }

#define STAGE(BUF, KT) do {                                                     \
    const int k0s = (KT) * 32;                                                  \
    _Pragma("unroll")                                                           \
    for (int i_ = 0; i_ < 2; ++i_) {                                            \
        const int rg   = wv + 4 * i_;                                           \
        const int rowl = rg * 16 + srow;                                        \
        const int chk  = sslot ^ ((rowl >> 1) & 3);                             \
        const size_t ka = (size_t)(m0 + rowl) * K + k0s + chk * 8;              \
        const size_t kw = (size_t)(n0 + rowl) * K + k0s + chk * 8;              \
        __builtin_amdgcn_global_load_lds(                                       \
            (const __attribute__((address_space(1))) void*)(Ah + ka),           \
            (__attribute__((address_space(3))) void*)(&lds[BUF][0][rg * 512]),  \
            16, 0, 0);                                                          \
        __builtin_amdgcn_global_load_lds(                                       \
            (const __attribute__((address_space(1))) void*)(Al + ka),           \
            (__attribute__((address_space(3))) void*)(&lds[BUF][1][rg * 512]),  \
            16, 0, 0);                                                          \
        __builtin_amdgcn_global_load_lds(                                       \
            (const __attribute__((address_space(1))) void*)(Wh + kw),           \
            (__attribute__((address_space(3))) void*)(&lds[BUF][2][rg * 512]),  \
            16, 0, 0);                                                          \
        __builtin_amdgcn_global_load_lds(                                       \
            (const __attribute__((address_space(1))) void*)(Wl + kw),           \
            (__attribute__((address_space(3))) void*)(&lds[BUF][3][rg * 512]),  \
            16, 0, 0);                                                          \
    } } while (0)

    f32x4 acc[4][4];
#pragma unroll
    for (int i = 0; i < 4; ++i)
#pragma unroll
        for (int j = 0; j < 4; ++j)
            acc[i][j] = (f32x4){0.f, 0.f, 0.f, 0.f};

    const int NT = K >> 5;
    STAGE(0, 0);
    __syncthreads();

    int buf = 0;
    for (int kt = 0; kt < NT; ++kt) {
        if (kt + 1 < NT) STAGE(buf ^ 1, kt + 1);

        const char* pAh = (const char*)&lds[buf][0][0];
        const char* pAl = (const char*)&lds[buf][1][0];
        const char* pWh = (const char*)&lds[buf][2][0];
        const char* pWl = (const char*)&lds[buf][3][0];
        bf16x8 ah[4], al[4], wh[4], wl[4];
#pragma unroll
        for (int f = 0; f < 4; ++f) {
            ah[f] = *(const bf16x8*)(pAh + aoff[f]);
            al[f] = *(const bf16x8*)(pAl + aoff[f]);
            wh[f] = *(const bf16x8*)(pWh + woff[f]);
            wl[f] = *(const bf16x8*)(pWl + woff[f]);
        }
#pragma unroll
        for (int fm = 0; fm < 4; ++fm)
#pragma unroll
            for (int fn = 0; fn < 4; ++fn) {
                acc[fm][fn] = __builtin_amdgcn_mfma_f32_16x16x32_bf16(
                    ah[fm], wh[fn], acc[fm][fn], 0, 0, 0);
                acc[fm][fn] = __builtin_amdgcn_mfma_f32_16x16x32_bf16(
                    ah[fm], wl[fn], acc[fm][fn], 0, 0, 0);
                acc[fm][fn] = __builtin_amdgcn_mfma_f32_16x16x32_bf16(
                    al[fm], wh[fn], acc[fm][fn], 0, 0, 0);
            }
        __syncthreads();
        buf ^= 1;
    }
#undef STAGE

    // epilogue: D row = (l>>4)*4 + r (+fm*16), col = l&15 (+fn*16)  [m89]
    const int orow = m0 + wm + ((l >> 4) << 2);
    const int ocol = n0 + wn + (l & 15);
    float bv[4];
#pragma unroll
    for (int fn = 0; fn < 4; ++fn) bv[fn] = bias[ocol + fn * 16];

#pragma unroll
    for (int fm = 0; fm < 4; ++fm)
#pragma unroll
        for (int fn = 0; fn < 4; ++fn)
#pragma unroll
            for (int r = 0; r < 4; ++r) {
                float v = acc[fm][fn][r] + bv[fn];
                if (ACT == 1) v = relu_(v);
                const size_t idx = (size_t)(orow + fm * 16 + r) * N + ocol + fn * 16;
                if (WMODE == 0 || WMODE == 1) C[idx] = v;
                if (WMODE == 1 || WMODE == 2) {
                    const __bf16 hh = (__bf16)v;
                    Ch[idx] = hh;
                    Cl[idx] = (__bf16)(v - (float)hh);
                }
            }
}

// ---------------------------------------------------------------------------
// Flash attention, fp32 compute. One block = (b, head, 64-row q-tile).
// Reads qkv f32 [B][S][3H]; writes ctx as SPLIT bf16 (hi/lo) [M][H].
// Softmax reductions are wave-parallel (4 lanes per row, shfl_xor tree).
// ---------------------------------------------------------------------------
__global__ __launch_bounds__(256) void attn_kernel(
    const float* __restrict__ qkv, __bf16* __restrict__ ctx_h,
    __bf16* __restrict__ ctx_l)
{
    __shared__ __align__(16) float Qs[64][72];   // [d][q]
    __shared__ __align__(16) float Ks[64][72];   // [d][k]
    __shared__ __align__(16) float Vs[64][72];   // [k][d]
    __shared__ __align__(16) float Ps[64][72];   // [k][q] swizzled
    __shared__ __align__(16) float red[64][20];  // 20-stride: float4 @ q*4 aligned
    __shared__ float mrow[64], lrow[64], cfrow[64];

    const int tid = threadIdx.x;
    const int gx  = blockIdx.x;
    const int qt  = gx & 7;
    const int h   = (gx >> 3) & 7;
    const int b   = gx >> 6;
    const int q0  = qt * 64;

    const size_t bh_off = (size_t)b * S_ * (3 * H_) + (size_t)h * HD_;
    const int ql = tid >> 4;
    const int dl = (tid & 15) << 2;
    const int tx = tid & 15;
    const int ty = tid >> 4;
    const int rr4 = tid >> 2;          // reduction row 0..63
    const int rq  = tid & 3;           // reduction quarter

#pragma unroll
    for (int r = 0; r < 4; ++r) {
        int q = r * 16 + ql;
        float4 v = *(const float4*)(qkv + bh_off + (size_t)(q0 + q) * (3 * H_) + dl);
        Qs[dl+0][q] = v.x; Qs[dl+1][q] = v.y; Qs[dl+2][q] = v.z; Qs[dl+3][q] = v.w;
    }
    if (tx == 0) {
#pragma unroll
        for (int i = 0; i < 4; ++i) { mrow[ty*4+i] = -1e30f; lrow[ty*4+i] = 0.f; }
    }
    float o[4][4] = {};
    __syncthreads();

    for (int kt = 0; kt < 8; ++kt) {
        const int k0 = kt * 64;
        __syncthreads();
#pragma unroll
        for (int r = 0; r < 4; ++r) {
            int k = r * 16 + ql;
            float4 kv = *(const float4*)(qkv + bh_off + H_     + (size_t)(k0 + k) * (3 * H_) + dl);
            Ks[dl+0][k] = kv.x; Ks[dl+1][k] = kv.y; Ks[dl+2][k] = kv.z; Ks[dl+3][k] = kv.w;
            float4 vv = *(const float4*)(qkv + bh_off + 2 * H_ + (size_t)(k0 + k) * (3 * H_) + dl);
            *(float4*)&Vs[k][dl] = vv;
        }
        __syncthreads();

        // S-tile = Q @ K^T * 1/sqrt(64)
        float s[4][4] = {};
#pragma unroll 8
        for (int d = 0; d < 64; ++d) {
            const float4 a4 = *(const float4*)&Qs[d][ty << 2];
            const float4 b4 = *(const float4*)&Ks[d][tx << 2];
            const float ar[4] = {a4.x, a4.y, a4.z, a4.w};
            const float br[4] = {b4.x, b4.y, b4.z, b4.w};
#pragma unroll
            for (int i = 0; i < 4; ++i)
#pragma unroll
                for (int j = 0; j < 4; ++j)
                    s[i][j] = fmaf(ar[i], br[j], s[i][j]);
        }
#pragma unroll
        for (int i = 0; i < 4; ++i) {
            float mx = -1e30f;
#pragma unroll
            for (int j = 0; j < 4; ++j) { s[i][j] *= 0.125f; mx = fmaxf(mx, s[i][j]); }
            red[ty*4+i][tx] = mx;
        }
        __syncthreads();
        {   // wave-parallel row-max: 4 lanes per row
            const float4 v = *(const float4*)&red[rr4][rq << 2];
            float mx = fmaxf(fmaxf(v.x, v.y), fmaxf(v.z, v.w));
            mx = fmaxf(mx, __shfl_xor(mx, 1));
            mx = fmaxf(mx, __shfl_xor(mx, 2));
            if (rq == 0) {
                const float mo = mrow[rr4];
                const float mn = fmaxf(mo, mx);
                const float cf = __expf(mo - mn);
                mrow[rr4] = mn; cfrow[rr4] = cf; lrow[rr4] *= cf;
            }
        }
        __syncthreads();
        // p = exp(s - m), rescale o, write P (chunk-rotated cols), rowsum partials
#pragma unroll
        for (int i = 0; i < 4; ++i) {
            int rr = ty*4 + i;
            float mn = mrow[rr], cf = cfrow[rr];
            float rs = 0.f;
#pragma unroll
            for (int j = 0; j < 4; ++j) {
                o[i][j] *= cf;
                float p = __expf(s[i][j] - mn);
                rs += p;
                int krow = 4*tx + j;
                Ps[krow][((ty<<2) + i + (krow & 60)) & 63] = p;
            }
            red[rr][tx] = rs;
        }
        __syncthreads();
        {   // wave-parallel row-sum
            const float4 v = *(const float4*)&red[rr4][rq << 2];
            float sm = v.x + v.y + v.z + v.w;
            sm += __shfl_xor(sm, 1);
            sm += __shfl_xor(sm, 2);
            if (rq == 0) lrow[rr4] += sm;
        }
        // O += P @ V
#pragma unroll 8
        for (int kk = 0; kk < 64; ++kk) {
            const int pc = ((ty << 2) + (kk & 60)) & 63;
            const float4 a4 = *(const float4*)&Ps[kk][pc];
            const float4 b4 = *(const float4*)&Vs[kk][tx << 2];
            const float ar[4] = {a4.x, a4.y, a4.z, a4.w};
            const float br[4] = {b4.x, b4.y, b4.z, b4.w};
#pragma unroll
            for (int i = 0; i < 4; ++i)
#pragma unroll
                for (int j = 0; j < 4; ++j)
                    o[i][j] = fmaf(ar[i], br[j], o[i][j]);
        }
    }
    __syncthreads();
#pragma unroll
    for (int i = 0; i < 4; ++i) {
        const int q = q0 + ty*4 + i;
        const float inv = 1.f / lrow[ty*4 + i];
        bf16x4 hv, lv;
#pragma unroll
        for (int j = 0; j < 4; ++j) {
            const float v = o[i][j] * inv;
            hv[j] = (__bf16)v;
            lv[j] = (__bf16)(v - (float)hv[j]);
        }
        const size_t idx = ((size_t)b * S_ + q) * H_ + h * HD_ + (tx << 2);
        *(bf16x4*)(ctx_h + idx) = hv;
        *(bf16x4*)(ctx_l + idx) = lv;
    }
}

// ---------------------------------------------------------------------------
// out = LN((ah+al) + r) * g + b, written as split bf16 (hi/lo).
// a is a split-bf16 pair (reconstructed hi+lo), r is f32.
// one wave per row (H=512), 4 rows per block.
// ---------------------------------------------------------------------------
__global__ __launch_bounds__(256) void add_ln_kernel(
    const __bf16* __restrict__ ah, const __bf16* __restrict__ al,
    const float* __restrict__ r,
    const float* __restrict__ g, const float* __restrict__ bb,
    __bf16* __restrict__ oh, __bf16* __restrict__ ol)
{
    const int lane = threadIdx.x & 63;
    const int row  = (blockIdx.x << 2) + (threadIdx.x >> 6);
    const size_t base = (size_t)row * H_;
    const int e0 = lane * 4;
    const int e1 = 256 + lane * 4;

    const bf16x4 ah0 = *(const bf16x4*)(ah + base + e0);
    const bf16x4 ah1 = *(const bf16x4*)(ah + base + e1);
    const bf16x4 al0 = *(const bf16x4*)(al + base + e0);
    const bf16x4 al1 = *(const bf16x4*)(al + base + e1);
    const float4 r0  = *(const float4*)(r + base + e0);
    const float4 r1  = *(const float4*)(r + base + e1);

    float x0[4], x1[4];
    const float rr0[4] = {r0.x, r0.y, r0.z, r0.w};
    const float rr1[4] = {r1.x, r1.y, r1.z, r1.w};
#pragma unroll
    for (int j = 0; j < 4; ++j) {
        x0[j] = (float)ah0[j] + (float)al0[j] + rr0[j];
        x1[j] = (float)ah1[j] + (float)al1[j] + rr1[j];
    }

    float sum = 0.f, sq = 0.f;
#pragma unroll
    for (int j = 0; j < 4; ++j) {
        sum += x0[j] + x1[j];
        sq  += x0[j]*x0[j] + x1[j]*x1[j];
    }
#pragma unroll
    for (int off = 1; off < 64; off <<= 1) {
        sum += __shfl_xor(sum, off);
        sq  += __shfl_xor(sq,  off);
    }
    const float mu  = sum * (1.0f / H_);
    const float var = sq  * (1.0f / H_) - mu * mu;
    const float rs  = rsqrtf(var + 1e-5f);

    const float4 g0 = *(const float4*)(g + e0);
    const float4 g1 = *(const float4*)(g + e1);
    const float4 b0 = *(const float4*)(bb + e0);
    const float4 b1 = *(const float4*)(bb + e1);
    const float gg0[4] = {g0.x, g0.y, g0.z, g0.w};
    const float gg1[4] = {g1.x, g1.y, g1.z, g1.w};
    const float bb0[4] = {b0.x, b0.y, b0.z, b0.w};
    const float bb1[4] = {b1.x, b1.y, b1.z, b1.w};

    bf16x4 h0, l0, h1, l1;
#pragma unroll
    for (int j = 0; j < 4; ++j) {
        const float y0 = (x0[j] - mu) * rs * gg0[j] + bb0[j];
        const float y1 = (x1[j] - mu) * rs * gg1[j] + bb1[j];
        h0[j] = (__bf16)y0; l0[j] = (__bf16)(y0 - (float)h0[j]);
        h1[j] = (__bf16)y1; l1[j] = (__bf16)(y1 - (float)h1[j]);
    }
    *(bf16x4*)(oh + base + e0) = h0;
    *(bf16x4*)(ol + base + e0) = l0;
    *(bf16x4*)(oh + base + e1) = h1;
    *(bf16x4*)(ol + base + e1) = l1;
}

// ---------------------------------------------------------------------------
// Distributed liquid-ODE scan: 4 blocks per batch (grid 128 x 512 thr).
// Each block owns a 128-col slice of rec_w, preloaded into REGISTERS
// (128 f32/thread; ~160 VGPR total, under the 256 cap from
// __launch_bounds__(512,2) so the 8-wave block is always schedulable;
// 128 blocks <= 256 CUs => co-resident).  Per step: reg-matvec (h broadcast
// from LDS) -> LDS quarter-reduce -> tanh update on 128 threads -> exchange
// slices via ping-pong global buffer + per-batch monotonic release/acquire
// flag (agent-scope atomics, coherent through L3 across XCDs).  Spin is
// bounded SMALL (2^14 polls ~ few ms) so any co-residency failure terminates
// quickly and observably instead of hanging the bench.
// thread t: col = slice*128 + (t&127), i-quarter q = t>>7 (128 i's).
// ---------------------------------------------------------------------------
__global__ __launch_bounds__(512, 2) void liquid_scan_kernel(
    const float* __restrict__ inp_proj, const float* __restrict__ rec_w,
    const float* __restrict__ tau, float* __restrict__ hglob,
    unsigned int* __restrict__ flags)
{
    __shared__ float h[H_];
    __shared__ float ps[4][128];

    const int t     = threadIdx.x;
    const int bb    = blockIdx.x;
    const int batch = bb & 31;
    const int slice = bb >> 5;          // 0..3
    const int cl    = t & 127;          // local col
    const int q     = t >> 7;           // i-quarter (wave-uniform)
    const int c     = slice * 128 + cl; // global col

    // preload this thread's weight column-slice: w[k] = rec_w[q*128+k][c]
    float w[128];
#pragma unroll
    for (int k = 0; k < 128; ++k)
        w[k] = rec_w[(size_t)(q * 128 + k) * H_ + c];

    const float itau = 1.f / tau[c];

    h[t] = 0.f;
    __syncthreads();

    unsigned int* flg  = flags + batch;
    const float*  xrow = inp_proj + (size_t)batch * S_ * H_;

    for (int step = 0; step < S_; ++step) {
        float* hg = hglob + (size_t)((step + 1) & 1) * B_ * H_ + (size_t)batch * H_;
        float xt = 0.f;
        if (t < 128) xt = xrow[(size_t)step * H_ + c];

        // matvec over this thread's i-quarter (h broadcast per wave)
        float acc = 0.f;
        const float4* h4 = (const float4*)&h[q << 7];
#pragma unroll
        for (int k4 = 0; k4 < 32; ++k4) {
            const float4 hv = h4[k4];
            acc = fmaf(hv.x, w[4 * k4 + 0], acc);
            acc = fmaf(hv.y, w[4 * k4 + 1], acc);
            acc = fmaf(hv.z, w[4 * k4 + 2], acc);
            acc = fmaf(hv.w, w[4 * k4 + 3], acc);
        }
        ps[q][cl] = acc;
        __syncthreads();

        if (t < 128) {
            const float a  = ps[0][cl] + ps[1][cl] + ps[2][cl] + ps[3][cl] + xt;
            const float hc = h[c];
            const float f  = tanh_fast(a);
            float nh = fmaf(f - hc * itau, DT_, hc);   // h + (-h/tau + f)*DT
            nh = fminf(fmaxf(nh, -10.f), 10.f);
            __hip_atomic_store(&hg[c], nh, __ATOMIC_RELAXED, __HIP_MEMORY_SCOPE_AGENT);
        }
        __syncthreads();   // intra-block order + drains vmcnt before release

        if (t == 0) {
            __hip_atomic_fetch_add(flg, 1u, __ATOMIC_RELEASE, __HIP_MEMORY_SCOPE_AGENT);
            const unsigned int target = 4u * (unsigned int)(step + 1);
            // bounded spin: healthy run converges in a handful of polls
            for (int it = 0; it < (1 << 14); ++it) {
                if (__hip_atomic_load(flg, __ATOMIC_ACQUIRE,
                                      __HIP_MEMORY_SCOPE_AGENT) >= target) break;
            }
        }
        __syncthreads();

        // reload full h (just-written buffer) for next step; ping-pong means
        // a fast block's next-step stores hit the OTHER buffer (no WAR race)
        h[t] = __hip_atomic_load(&hg[t], __ATOMIC_RELAXED, __HIP_MEMORY_SCOPE_AGENT);
        __syncthreads();
    }
    // final state (step 512 even -> buffer 0) is in hglob[0..B*H)
}

// ---------------------------------------------------------------------------
// out[b] = hT[b] . fc_w[0] + fc_b[0]   (OUT=1)
// ---------------------------------------------------------------------------
__global__ __launch_bounds__(256) void fc_kernel(
    const float* __restrict__ hT, const float* __restrict__ fc_w,
    const float* __restrict__ fc_b, float* __restrict__ out)
{
    const int tid = threadIdx.x;
    const int b   = tid >> 3;
    const int seg = tid & 7;
    float acc = 0.f;
#pragma unroll 4
    for (int i = 0; i < 64; ++i)
        acc = fmaf(hT[(size_t)b * H_ + seg * 64 + i], fc_w[seg * 64 + i], acc);
    acc += __shfl_xor(acc, 1);
    acc += __shfl_xor(acc, 2);
    acc += __shfl_xor(acc, 4);
    if (seg == 0) out[b] = acc + fc_b[0];
}

// ---------------------------------------------------------------------------
extern "C" void kernel_launch(void* const* d_in, const int* in_sizes, int n_in,
                              void* d_out, int out_size, void* d_ws, size_t ws_size,
                              hipStream_t stream)
{
    (void)in_sizes; (void)n_in; (void)out_size;

    const float* x      = (const float*)d_in[0];
    const float* w_proj = (const float*)d_in[1];
    const float* b_proj = (const float*)d_in[2];
    const float* in_w   = (const float*)d_in[3];
    const float* in_b   = (const float*)d_in[4];
    const float* out_w  = (const float*)d_in[5];
    const float* out_b  = (const float*)d_in[6];
    const float* ln1_g  = (const float*)d_in[7];
    const float* ln1_b  = (const float*)d_in[8];
    const float* ln2_g  = (const float*)d_in[9];
    const float* ln2_b  = (const float*)d_in[10];
    const float* ff_w1  = (const float*)d_in[11];
    const float* ff_b1  = (const float*)d_in[12];
    const float* ff_w2  = (const float*)d_in[13];
    const float* ff_b2  = (const float*)d_in[14];
    const float* liq_w  = (const float*)d_in[15];
    const float* liq_b  = (const float*)d_in[16];
    const float* tau    = (const float*)d_in[17];
    const float* rec_w  = (const float*)d_in[18];
    const float* fc_w   = (const float*)d_in[19];
    const float* fc_b   = (const float*)d_in[20];

    // ---------------- workspace layout (byte offsets), ~250 MB total --------
    // lifetimes per layer:
    //   qkv_f(0-96) -> attn(ctx 96-128) -> attnout(0-32) -> ln1 ->
    //   f1(0-128, overlays dead qkv/attnout/ctx) -> ff2out(128-160) -> ln2
    // x split (proj input) overlays the later-written x1 slot; scan's
    // hglob/flags overlay the dead attnout/f1 slot at scan time.
    const size_t MBy = 1024 * 1024;
    char* base = (char*)d_ws;
    float*  qkv_f   = (float*) (base + 0);          // 96MB  [M][1536]
    __bf16* ctx_h   = (__bf16*)(base + 96  * MBy);  // 16MB
    __bf16* ctx_l   = (__bf16*)(base + 112 * MBy);  // 16MB
    float*  attnout = (float*) (base + 0);          // 32MB (reuses dead qkv)
    __bf16* f1_h    = (__bf16*)(base + 0);          // 64MB [M][2048]
    __bf16* f1_l    = (__bf16*)(base + 64  * MBy);  // 64MB (covers dead ctx)
    float*  ff2out  = (float*) (base + 128 * MBy);  // 32MB (also inp_proj)
    __bf16* h_h     = (__bf16*)(base + 160 * MBy);  // 16MB
    __bf16* h_l     = (__bf16*)(base + 176 * MBy);  // 16MB
    __bf16* x1_h    = (__bf16*)(base + 192 * MBy);  // 16MB
    __bf16* x1_l    = (__bf16*)(base + 208 * MBy);  // 16MB
    float*  hglob   = (float*) (base + 0);          // 128KB: 2 x [32][512] f32
    unsigned int* flags = (unsigned int*)(base + 132 * 1024);  // 128B
    __bf16* x_h     = (__bf16*)(base + 192 * MBy);  // 4MB (dead before x1_h)
    __bf16* x_l     = (__bf16*)(base + 196 * MBy);  // 4MB
    char* wp = base + 224 * MBy;

    auto take = [&](size_t nelem) {
        __bf16* p = (__bf16*)wp;
        wp += nelem * sizeof(__bf16);
        return p;
    };
    const size_t n_wproj = (size_t)H_ * IN_;
    const size_t n_inw   = (size_t)NL_ * 3 * H_ * H_;
    const size_t n_outw  = (size_t)NL_ * H_ * H_;
    const size_t n_ffw1  = (size_t)NL_ * FF_ * H_;
    const size_t n_ffw2  = (size_t)NL_ * H_ * FF_;
    const size_t n_liqw  = (size_t)H_ * H_;
    const size_t n_x     = (size_t)M_ * IN_;
    __bf16* wproj_h = take(n_wproj); __bf16* wproj_l = take(n_wproj);
    __bf16* inw_h   = take(n_inw);   __bf16* inw_l   = take(n_inw);
    __bf16* outw_h  = take(n_outw);  __bf16* outw_l  = take(n_outw);
    __bf16* ffw1_h  = take(n_ffw1);  __bf16* ffw1_l  = take(n_ffw1);
    __bf16* ffw2_h  = take(n_ffw2);  __bf16* ffw2_l  = take(n_ffw2);
    __bf16* liqw_h  = take(n_liqw);  __bf16* liqw_l  = take(n_liqw);
    if ((size_t)(wp - base) > ws_size) return;  // workspace too small

    const dim3 blk(256);

    // ---- weight/input split conversions ----
    auto split = [&](const float* s, __bf16* h, __bf16* l, size_t n) {
        split_kernel<<<dim3((unsigned)(n / 1024)), blk, 0, stream>>>(s, h, l, (int)n);
    };
    split(w_proj, wproj_h, wproj_l, n_wproj);
    split(in_w,   inw_h,   inw_l,   n_inw);
    split(out_w,  outw_h,  outw_l,  n_outw);
    split(ff_w1,  ffw1_h,  ffw1_l,  n_ffw1);
    split(ff_w2,  ffw2_h,  ffw2_l,  n_ffw2);
    split(liq_w,  liqw_h,  liqw_l,  n_liqw);
    split(x,      x_h,     x_l,     n_x);

    // ---- h = x @ w_proj^T + b_proj  (split out only) ----
    gemm_split_kernel<0, 2><<<dim3(H_ / 128, M_ / 128), blk, 0, stream>>>(
        x_h, x_l, wproj_h, wproj_l, b_proj, nullptr, h_h, h_l, M_, H_, IN_);

    for (int l = 0; l < NL_; ++l) {
        const size_t wq = (size_t)l * 3 * H_ * H_;
        const size_t wo = (size_t)l * H_ * H_;
        const size_t w1 = (size_t)l * FF_ * H_;
        const size_t w2 = (size_t)l * H_ * FF_;
        // qkv (f32 out)
        gemm_split_kernel<0, 0><<<dim3(3 * H_ / 128, M_ / 128), blk, 0, stream>>>(
            h_h, h_l, inw_h + wq, inw_l + wq, in_b + (size_t)l * 3 * H_,
            qkv_f, nullptr, nullptr, M_, 3 * H_, H_);
        // attention -> ctx split
        attn_kernel<<<dim3(B_ * NH_ * (S_ / 64)), blk, 0, stream>>>(qkv_f, ctx_h, ctx_l);
        // attn_out (f32)
        gemm_split_kernel<0, 0><<<dim3(H_ / 128, M_ / 128), blk, 0, stream>>>(
            ctx_h, ctx_l, outw_h + wo, outw_l + wo, out_b + (size_t)l * H_,
            attnout, nullptr, nullptr, M_, H_, H_);
        // x1 = LN(h + attn_out), split out
        add_ln_kernel<<<dim3(M_ / 4), blk, 0, stream>>>(
            h_h, h_l, attnout, ln1_g + (size_t)l * H_, ln1_b + (size_t)l * H_,
            x1_h, x1_l);
        // ff1 = relu(x1 @ w1^T + b1), split only
        gemm_split_kernel<1, 2><<<dim3(FF_ / 128, M_ / 128), blk, 0, stream>>>(
            x1_h, x1_l, ffw1_h + w1, ffw1_l + w1, ff_b1 + (size_t)l * FF_,
            nullptr, f1_h, f1_l, M_, FF_, H_);
        // ff2 (f32)
        gemm_split_kernel<0, 0><<<dim3(H_ / 128, M_ / 128), blk, 0, stream>>>(
            f1_h, f1_l, ffw2_h + w2, ffw2_l + w2, ff_b2 + (size_t)l * H_,
            ff2out, nullptr, nullptr, M_, H_, FF_);
        // h = LN(x1 + ff2), split out
        add_ln_kernel<<<dim3(M_ / 4), blk, 0, stream>>>(
            x1_h, x1_l, ff2out, ln2_g + (size_t)l * H_, ln2_b + (size_t)l * H_,
            h_h, h_l);
    }

    // inp_proj = h @ liq_w^T + liq_b (f32) -> ff2out slot
    gemm_split_kernel<0, 0><<<dim3(H_ / 128, M_ / 128), blk, 0, stream>>>(
        h_h, h_l, liqw_h, liqw_l, liq_b, ff2out, nullptr, nullptr, M_, H_, H_);

    // liquid scan: 4 blocks per batch, weights in registers, flag-synced.
    // flags MUST be zeroed every call (ws re-poisoned to 0xAA before replay).
    hipMemsetAsync(flags, 0, B_ * sizeof(unsigned int), stream);
    liquid_scan_kernel<<<dim3(4 * B_), dim3(512), 0, stream>>>(
        ff2out, rec_w, tau, hglob, flags);

    // final fc: final h is in hglob buffer 0
    fc_kernel<<<dim3(1), blk, 0, stream>>>(hglob, fc_w, fc_b, (float*)d_out);
}